// Round 6
// baseline (92.887 us; speedup 1.0000x reference)
//
#include <hip/hip_runtime.h>

// PhaseLinear: out[b,o] = sum_c coef[b,c] * (sum_i in[b,i]*W[c,o,i] + bias[c,o])
// All-f32 in / f32 out (verified r4), bf16 MFMA internally (absmax 0.031).
// Round 6: direct-from-global fragments (no LDS W round-trip — W has zero
// intra-block reuse) + register blocking BM=64 (4 m-frags/wave):
//   - W cache traffic halves vs r5 (16 b-tiles x 4 MB = 64 MB)
//   - 8 independent 32B loads feed 16 MFMAs per K-step (deep ILP)
//   - grid (8,16)=128 blocks x 256 thr, ~0.5 us MFMA per wave

#define BATCH 1024
#define IN_F  512
#define OUT_F 512

constexpr int BM = 64;            // batch rows per block (4 m-frags per wave)
constexpr int BO = 64;            // out features per block (4 waves x 16)
constexpr int BK = 32;            // K per MFMA step
constexpr int KITERS = IN_F / BK; // 16

typedef __bf16 bf16x8 __attribute__((ext_vector_type(8)));
typedef float  f32x4  __attribute__((ext_vector_type(4)));
typedef float  f32x8  __attribute__((ext_vector_type(8)));

__device__ __forceinline__ bf16x8 cvt8(f32x8 v) {   // RNE, v_cvt_pk_bf16_f32
  bf16x8 r;
#pragma unroll
  for (int i = 0; i < 8; ++i) r[i] = (__bf16)v[i];
  return r;
}

__global__ __launch_bounds__(256)
void PhaseLinear_kernel(const float* __restrict__ inp, const float* __restrict__ ph,
                        const float* __restrict__ wts, const float* __restrict__ bia,
                        float* __restrict__ outp) {
  __shared__ float sCoef[BM][4];

  const int tid = threadIdx.x;
  const int wv  = tid >> 6;        // wave 0..3 -> 16-out slice
  const int l   = tid & 63;
  const int o0  = blockIdx.x * BO;
  const int b0  = blockIdx.y * BM;

  // --- spline coefficients (replicates reference tt=[1,t^2,t^3,0] bug) ---
  if (tid < BM) {
    const float PI = 3.14159265358979323846f;
    float p  = ph[b0 + tid];
    float t  = (p < 1.5f * PI) ? (p / (1.5f * PI)) : ((p - 0.5f * PI) / (1.5f * PI));
    float t2 = t * t, t3 = t2 * t;
    sCoef[tid][0] = t3 - 0.5f * t2;        // tt @ (0.5*CATMULL_ROM_BASIS)
    sCoef[tid][1] = 1.0f - 2.5f * t3;
    sCoef[tid][2] = 0.5f * t2 + 2.0f * t3;
    sCoef[tid][3] = -0.5f * t3;
  }
  __syncthreads();                 // only barrier in the kernel

  const int n = l & 15;            // M index (A) / N index (B) / col of C
  const int q = l >> 4;            // k-quad (0..3), k-span q*8..q*8+8

  // per-lane global fragment pointers (32B contiguous each)
  const float* pa[4];
#pragma unroll
  for (int mf = 0; mf < 4; ++mf)
    pa[mf] = inp + (size_t)(b0 + mf * 16 + n) * IN_F + q * 8;
  const float* pw[4];
#pragma unroll
  for (int c = 0; c < 4; ++c)
    pw[c] = wts + ((size_t)c * OUT_F + o0 + wv * 16 + n) * IN_F + q * 8;

  f32x4 acc[4][4];                 // [m-frag][ctrl-pt]
#pragma unroll
  for (int m = 0; m < 4; ++m)
#pragma unroll
    for (int c = 0; c < 4; ++c) acc[m][c] = (f32x4){0.f, 0.f, 0.f, 0.f};

  // prefetch K-step 0 (8 independent 32B loads)
  f32x8 curA[4], curW[4];
#pragma unroll
  for (int m = 0; m < 4; ++m) curA[m] = *(const f32x8*)(pa[m]);
#pragma unroll
  for (int c = 0; c < 4; ++c) curW[c] = *(const f32x8*)(pw[c]);

#pragma unroll
  for (int kk = 0; kk < KITERS; ++kk) {
    // issue next step's loads first (no barrier: vmcnt-scheduled pipeline)
    f32x8 nxtA[4], nxtW[4];
    if (kk + 1 < KITERS) {
      const int off = (kk + 1) * BK;
#pragma unroll
      for (int m = 0; m < 4; ++m) nxtA[m] = *(const f32x8*)(pa[m] + off);
#pragma unroll
      for (int c = 0; c < 4; ++c) nxtW[c] = *(const f32x8*)(pw[c] + off);
    }
    bf16x8 af[4];
#pragma unroll
    for (int m = 0; m < 4; ++m) af[m] = cvt8(curA[m]);
#pragma unroll
    for (int c = 0; c < 4; ++c) {
      bf16x8 wf = cvt8(curW[c]);
#pragma unroll
      for (int m = 0; m < 4; ++m)
        acc[m][c] = __builtin_amdgcn_mfma_f32_16x16x32_bf16(af[m], wf, acc[m][c], 0, 0, 0);
    }
#pragma unroll
    for (int j = 0; j < 4; ++j) { curA[j] = nxtA[j]; curW[j] = nxtW[j]; }
  }

  // --- epilogue: blend 4 control points + bias, f32 store ---
  // C/D layout (m89/m91 verified): col = l&15, row = (l>>4)*4 + reg
  const int o = o0 + wv * 16 + n;
  float bs[4];
#pragma unroll
  for (int c = 0; c < 4; ++c) bs[c] = bia[c * OUT_F + o];

#pragma unroll
  for (int mf = 0; mf < 4; ++mf) {
#pragma unroll
    for (int r = 0; r < 4; ++r) {
      const int bl = mf * 16 + q * 4 + r;
      float v = 0.f;
#pragma unroll
      for (int c = 0; c < 4; ++c)
        v += sCoef[bl][c] * (acc[mf][c][r] + bs[c]);
      outp[(size_t)(b0 + bl) * OUT_F + o] = v;
    }
  }
}

extern "C" void kernel_launch(void* const* d_in, const int* in_sizes, int n_in,
                              void* d_out, int out_size, void* d_ws, size_t ws_size,
                              hipStream_t stream) {
  const float* inp = (const float*)d_in[0];   // input  (1024, 512) f32
  const float* ph  = (const float*)d_in[1];   // phase  (1024,)     f32
  const float* wts = (const float*)d_in[2];   // weights(4,512,512) f32
  const float* bia = (const float*)d_in[3];   // biases (4,512)     f32
  float* outp = (float*)d_out;                // out    (1024,512)  f32

  dim3 grid(OUT_F / BO, BATCH / BM);          // (8, 16) = 128 blocks
  PhaseLinear_kernel<<<grid, 256, 0, stream>>>(inp, ph, wts, bia, outp);
}

// Round 7
// 78.186 us; speedup vs baseline: 1.1880x; 1.1880x over previous
//
#include <hip/hip_runtime.h>

// PhaseLinear: out[b,o] = sum_c coef[b,c] * (sum_i in[b,i]*W[c,o,i] + bias[c,o])
// All-f32 in / f32 out (verified r4), bf16 MFMA internally (absmax 0.031).
// Round 7 theory: r5/r6 regressions were VGPR-pressure spills (full-unroll
// hoisting of prefetch sets) + f32 re-fetch volume. Fix:
//  1. pre-convert A,W -> bf16 into d_ws (halves GEMM fetch, removes loop cvt)
//  2. tile BM=64 x BO=32, grid(16,16): total fetch ~48 MB (vs r4 ~147 MB)
//  3. hand ping-pong prefetch, #pragma unroll 1: peak live ~110 VGPR, no spill,
//     zero K-loop barriers.

#define BATCH 1024
#define IN_F  512
#define OUT_F 512

constexpr int BM = 64;            // batch rows per block (2 waves x 2 m-frags)
constexpr int BO = 32;            // out features per block (2 waves x 16)
constexpr int BK = 32;            // K per MFMA step
constexpr int KITERS = IN_F / BK; // 16

constexpr int A_VECS = BATCH * IN_F / 4;          // 131072 f32x4 vecs
constexpr int W_VECS = 4 * OUT_F * IN_F / 4;      // 262144
constexpr int CVT_VECS = A_VECS + W_VECS;         // 393216
constexpr size_t WS_A = 0;                        // bf16 A: 1 MB
constexpr size_t WS_W = (size_t)BATCH * IN_F;     // elem offset of bf16 W

typedef unsigned short u16;
typedef __bf16 bf16x4 __attribute__((ext_vector_type(4)));
typedef __bf16 bf16x8 __attribute__((ext_vector_type(8)));
typedef float  f32x4  __attribute__((ext_vector_type(4)));

// ---------- kernel 1: f32 -> bf16 pre-convert into workspace ----------
__global__ __launch_bounds__(256)
void cvt_kernel(const float* __restrict__ inp, const float* __restrict__ wts,
                __bf16* __restrict__ ws) {
  int v = blockIdx.x * 256 + threadIdx.x;
  if (v >= CVT_VECS) return;
  const float* src; __bf16* dst;
  if (v < A_VECS) { src = inp + (size_t)v * 4;            dst = ws + WS_A + (size_t)v * 4; }
  else { int u = v - A_VECS; src = wts + (size_t)u * 4;   dst = ws + WS_W + (size_t)u * 4; }
  f32x4 x = *(const f32x4*)src;
  bf16x4 y;
#pragma unroll
  for (int i = 0; i < 4; ++i) y[i] = (__bf16)x[i];   // RNE v_cvt
  *(bf16x4*)dst = y;
}

// ---------- kernel 2: fused bf16 MFMA GEMM + spline blend ----------
struct Frag { bf16x8 a0, a1, w0, w1, w2, w3; };

__global__ __launch_bounds__(256)
void PhaseLinear_kernel(const __bf16* __restrict__ ws, const float* __restrict__ ph,
                        const float* __restrict__ bia, float* __restrict__ outp) {
  __shared__ float sCoef[BM][4];

  const int tid = threadIdx.x;
  const int wv  = tid >> 6;        // wave 0..3
  const int wm  = wv & 1;          // m-half (32 rows)
  const int wo  = wv >> 1;         // o-half (16 outs)
  const int l   = tid & 63;
  const int o0  = blockIdx.x * BO;
  const int b0  = blockIdx.y * BM;

  // --- spline coefficients (replicates reference tt=[1,t^2,t^3,0] bug) ---
  if (tid < BM) {
    const float PI = 3.14159265358979323846f;
    float p  = ph[b0 + tid];
    float t  = (p < 1.5f * PI) ? (p / (1.5f * PI)) : ((p - 0.5f * PI) / (1.5f * PI));
    float t2 = t * t, t3 = t2 * t;
    sCoef[tid][0] = t3 - 0.5f * t2;        // tt @ (0.5*CATMULL_ROM_BASIS)
    sCoef[tid][1] = 1.0f - 2.5f * t3;
    sCoef[tid][2] = 0.5f * t2 + 2.0f * t3;
    sCoef[tid][3] = -0.5f * t3;
  }
  __syncthreads();                 // only barrier in the kernel

  const int n = l & 15;            // M index (A) / N index (B) / col of C
  const int q = l >> 4;            // k-quad, k-span q*8..q*8+8

  // per-lane bf16 fragment pointers (16B contiguous each)
  const __bf16* pa0 = ws + WS_A + (size_t)(b0 + wm * 32 + n) * IN_F + q * 8;
  const __bf16* pa1 = pa0 + (size_t)16 * IN_F;
  const __bf16* pw[4];
#pragma unroll
  for (int c = 0; c < 4; ++c)
    pw[c] = ws + WS_W + ((size_t)c * OUT_F + o0 + wo * 16 + n) * IN_F + q * 8;

  auto load6 = [&](int kk) -> Frag {
    const int off = kk * BK;
    Frag f;
    f.a0 = *(const bf16x8*)(pa0 + off);
    f.a1 = *(const bf16x8*)(pa1 + off);
    f.w0 = *(const bf16x8*)(pw[0] + off);
    f.w1 = *(const bf16x8*)(pw[1] + off);
    f.w2 = *(const bf16x8*)(pw[2] + off);
    f.w3 = *(const bf16x8*)(pw[3] + off);
    return f;
  };

  f32x4 acc[2][4];                 // [m-frag][ctrl-pt]
#pragma unroll
  for (int m = 0; m < 2; ++m)
#pragma unroll
    for (int c = 0; c < 4; ++c) acc[m][c] = (f32x4){0.f, 0.f, 0.f, 0.f};

  auto mfma6 = [&](const Frag& f) {
    acc[0][0] = __builtin_amdgcn_mfma_f32_16x16x32_bf16(f.a0, f.w0, acc[0][0], 0, 0, 0);
    acc[1][0] = __builtin_amdgcn_mfma_f32_16x16x32_bf16(f.a1, f.w0, acc[1][0], 0, 0, 0);
    acc[0][1] = __builtin_amdgcn_mfma_f32_16x16x32_bf16(f.a0, f.w1, acc[0][1], 0, 0, 0);
    acc[1][1] = __builtin_amdgcn_mfma_f32_16x16x32_bf16(f.a1, f.w1, acc[1][1], 0, 0, 0);
    acc[0][2] = __builtin_amdgcn_mfma_f32_16x16x32_bf16(f.a0, f.w2, acc[0][2], 0, 0, 0);
    acc[1][2] = __builtin_amdgcn_mfma_f32_16x16x32_bf16(f.a1, f.w2, acc[1][2], 0, 0, 0);
    acc[0][3] = __builtin_amdgcn_mfma_f32_16x16x32_bf16(f.a0, f.w3, acc[0][3], 0, 0, 0);
    acc[1][3] = __builtin_amdgcn_mfma_f32_16x16x32_bf16(f.a1, f.w3, acc[1][3], 0, 0, 0);
  };

  // ping-pong prefetch, unroll capped: peak live = 2 frag sets (48 VGPR)
  Frag cur = load6(0);
#pragma unroll 1
  for (int kk = 0; kk < KITERS; kk += 2) {
    Frag nxt = load6(kk + 1);              // kk+1 <= 15, always valid
    mfma6(cur);
    if (kk + 2 < KITERS) cur = load6(kk + 2);
    mfma6(nxt);
  }

  // --- epilogue: blend 4 control points + bias, f32 store ---
  // C/D layout (m89/m91 verified): col = l&15, row = (l>>4)*4 + reg
  const int o = o0 + wo * 16 + n;
  float bs[4];
#pragma unroll
  for (int c = 0; c < 4; ++c) bs[c] = bia[c * OUT_F + o];

#pragma unroll
  for (int mf = 0; mf < 2; ++mf) {
#pragma unroll
    for (int r = 0; r < 4; ++r) {
      const int bl = wm * 32 + mf * 16 + q * 4 + r;
      float v = 0.f;
#pragma unroll
      for (int c = 0; c < 4; ++c)
        v += sCoef[bl][c] * (acc[mf][c][r] + bs[c]);
      outp[(size_t)(b0 + bl) * OUT_F + o] = v;
    }
  }
}

extern "C" void kernel_launch(void* const* d_in, const int* in_sizes, int n_in,
                              void* d_out, int out_size, void* d_ws, size_t ws_size,
                              hipStream_t stream) {
  const float* inp = (const float*)d_in[0];   // input  (1024, 512) f32
  const float* ph  = (const float*)d_in[1];   // phase  (1024,)     f32
  const float* wts = (const float*)d_in[2];   // weights(4,512,512) f32
  const float* bia = (const float*)d_in[3];   // biases (4,512)     f32
  float* outp = (float*)d_out;                // out    (1024,512)  f32
  __bf16* ws = (__bf16*)d_ws;                 // bf16 A (1MB) + bf16 W (2MB)

  cvt_kernel<<<(CVT_VECS + 255) / 256, 256, 0, stream>>>(inp, wts, ws);

  dim3 grid(OUT_F / BO, BATCH / BM);          // (16, 16) = 256 blocks
  PhaseLinear_kernel<<<grid, 256, 0, stream>>>(ws, ph, bia, outp);
}